// Round 13
// baseline (180.956 us; speedup 1.0000x reference)
//
#include <hip/hip_runtime.h>

#define LRELU_ALPHA 0.2f

typedef __bf16 bf16x8 __attribute__((ext_vector_type(8)));
typedef unsigned short u16;
typedef unsigned short u16x8 __attribute__((ext_vector_type(8)));
typedef float f32x4 __attribute__((ext_vector_type(4)));
typedef int int4v __attribute__((ext_vector_type(4)));
typedef unsigned int u32;
typedef unsigned long long u64;

__device__ __forceinline__ u16 f2bf(float f) {
  unsigned int u = __float_as_uint(f);
  u += 0x7fffu + ((u >> 16) & 1u);   // RNE
  return (u16)(u >> 16);
}

// ---------------- kernel 1: WbT[o][i] = bf16(W[i][o]) ----------------
__global__ __launch_bounds__(256) void wcast(const float* __restrict__ W,
                                             u16* __restrict__ WbT) {
  int idx = blockIdx.x * 256 + threadIdx.x;            // 65536
  WbT[idx] = f2bf(W[(idx & 255) * 256 + (idx >> 8)]);
}

// ------- kernel 2: fused gemm1 (blocks 0..255) + packadj (256..4351) --
// Pack: int4 coalesced loads (1KB/wave-instr) + 4 ballots. Bit layout:
// column c of row -> u64 word row*64 + (c>>8)*4 + (c&3), bit (c>>2)&63.
// gemm1 writes HhTt in the R6-verified tiled layout (u16 index):
// b*2^20 + (kk>>5)*8192 + (col>>4)*512 + ((kk>>3)&3)*128 + (col&15)*8 + (kk&7)
__global__ __launch_bounds__(256) void packgemm(const int* __restrict__ adj,
                                                u32* __restrict__ maskg,
                                                const float* __restrict__ h,
                                                const u16* __restrict__ WbT,
                                                const float* __restrict__ a,
                                                u16* __restrict__ HhTt,
                                                float* __restrict__ sbuf,
                                                float* __restrict__ dbuf) {
  const int tid = threadIdx.x;
  const int l = tid & 63, w = tid >> 6;

  if (blockIdx.x >= 256) {
    // ---- pack: 4 rows/block (1 per wave), int4 + ballot ----
    const size_t row = (size_t)(blockIdx.x - 256) * 4 + w;   // 0..16383
    const int* arow = adj + row * 4096;
    u64* mrow = (u64*)maskg + row * 64;
    for (int ch = 0; ch < 16; ++ch) {
      int4v v = *(const int4v*)(arow + ch * 256 + l * 4);
      u64 b0 = __ballot(v.x != 0);
      u64 b1 = __ballot(v.y != 0);
      u64 b2 = __ballot(v.z != 0);
      u64 b3 = __ballot(v.w != 0);
      if (l == 0) {
        mrow[ch * 4 + 0] = b0;
        mrow[ch * 4 + 1] = b1;
        mrow[ch * 4 + 2] = b2;
        mrow[ch * 4 + 3] = b3;
      }
    }
    return;
  }

  // ---- gemm1 (R8/R12-proven, byte-identical) ----
  const int bid = blockIdx.x;
  const int lr = l & 15;
  const int lk = (l >> 4) << 3;
  const int rowA = bid * 64 + 16 * w + lr;
  const float* hrow = h + (size_t)rowA * 256 + lk;

  f32x4 acc[16];
#pragma unroll
  for (int n = 0; n < 16; ++n) acc[n] = (f32x4){0.f, 0.f, 0.f, 0.f};

  for (int k0 = 0; k0 < 256; k0 += 32) {
    f32x4 a0 = *(const f32x4*)(hrow + k0);
    f32x4 a1 = *(const f32x4*)(hrow + k0 + 4);
    u16x8 au;
    au[0] = f2bf(a0[0]); au[1] = f2bf(a0[1]); au[2] = f2bf(a0[2]); au[3] = f2bf(a0[3]);
    au[4] = f2bf(a1[0]); au[5] = f2bf(a1[1]); au[6] = f2bf(a1[2]); au[7] = f2bf(a1[3]);
    bf16x8 af = __builtin_bit_cast(bf16x8, au);
#pragma unroll
    for (int n = 0; n < 16; ++n) {
      int4v bv = *(const int4v*)(WbT + (size_t)(16 * n + lr) * 256 + k0 + lk);
      bf16x8 bf = __builtin_bit_cast(bf16x8, bv);
      acc[n] = __builtin_amdgcn_mfma_f32_16x16x32_bf16(af, bf, acc[n], 0, 0, 0);
    }
  }

  float sp[4] = {0.f, 0.f, 0.f, 0.f}, dp[4] = {0.f, 0.f, 0.f, 0.f};
#pragma unroll
  for (int n = 0; n < 16; ++n) {
    int col = 16 * n + lr;
    float as = a[col];
    float ad = a[256 + col];
#pragma unroll
    for (int rr = 0; rr < 4; ++rr) {
      int row = bid * 64 + 16 * w + ((l >> 4) << 2) + rr;
      int bb = row >> 12, kk = row & 4095;
      float v = acc[n][rr];
      size_t addr = (size_t)bb * 1048576 + (size_t)(kk >> 5) * 8192 +
                    (col >> 4) * 512 + ((kk >> 3) & 3) * 128 + (col & 15) * 8 +
                    (kk & 7);
      HhTt[addr] = f2bf(v);
      sp[rr] += v * as;
      dp[rr] += v * ad;
    }
  }
#pragma unroll
  for (int rr = 0; rr < 4; ++rr) {
#pragma unroll
    for (int off = 1; off < 16; off <<= 1) {
      sp[rr] += __shfl_xor(sp[rr], off);
      dp[rr] += __shfl_xor(dp[rr], off);
    }
  }
  if ((l & 15) == 0) {
#pragma unroll
    for (int rr = 0; rr < 4; ++rr) {
      int row = bid * 64 + 16 * w + ((l >> 4) << 2) + rr;
      sbuf[row] = sp[rr];
      dbuf[row] = dp[rr];
    }
  }
}

// ---------------- kernel 3: main fused GAT aggregation ----------------
// R12-identical structure: grid 256 (1/CU), 1024 thr / 16 waves.
// BM=64 x BN=256; wave w = col-tile (B dup x1). e-gen ONCE per element
// into 4-buffer At; one raw s_barrier + lgkmcnt(0)/step; B free-floats
// from L2 with depth-1 register prefetch. Only change vs R12: Mk layout
// (stride-131, no rotation) + 2-word interleaved-bit extraction.
__global__ __launch_bounds__(1024, 4) void gat_main(const u32* __restrict__ maskg,
                                                    const u16* __restrict__ HhTt,
                                                    const float* __restrict__ s,
                                                    const float* __restrict__ d,
                                                    float* __restrict__ out) {
  __shared__ __align__(16) u32 Mk[64 * 131];   // 33.5 KB mask panel (pad 131)
  __shared__ __align__(16) u16 At[4][2560];    // 20 KB: [buf][row64][k32+pad8]
  __shared__ float rs_lds[64];

  const int tid = threadIdx.x, bid = blockIdx.x;
  const int xcd = bid & 7;
  const int t = (xcd << 5) | (bid >> 3);       // 0..255 bijective
  const int b = t >> 6;                        // batch -> 2 XCDs
  const int rowbase = (t & 63) << 6;

  const int l = tid & 63, w = tid >> 6;        // w 0..15 = col-tile
  const int lr = l & 15, lkg = l >> 4;
  const int r = tid >> 4, kp = tid & 15;       // e-gen: row r, k-pair kp

  // ---- stage mask panel (no rotation) ----
  {
    const u32* mrow = maskg + ((size_t)(b * 4096 + rowbase)) * 128;
#pragma unroll
    for (int j = 0; j < 8; ++j)
      Mk[r * 131 + kp * 8 + j] = mrow[r * 128 + kp * 8 + j];
  }
  const float s_r = s[b * 4096 + rowbase + r];
  const float* dtp = d + b * 4096 + kp * 2;    // 8B per step, L1-resident
  const int mkr = r * 131;

  float racc = 0.f;

// columns c = STE*32 + kp*2 + {0,1}:
//   u32 word  = (STE>>3)*8 + (kp&1)*4 + ((STE&7)>>2)  (+2 for second col)
//   bit       = (STE&3)*8 + (kp>>1)
#define EGEN(BUF, STE)                                                        \
  {                                                                           \
    const int wb_ = ((STE) >> 3) * 8 + (kp & 1) * 4 + (((STE) & 7) >> 2);     \
    const int bp_ = ((STE) & 3) * 8 + (kp >> 1);                              \
    u32 w0_ = Mk[mkr + wb_];                                                  \
    u32 w1_ = Mk[mkr + wb_ + 2];                                              \
    float2 dv = *(const float2*)(dtp + (STE) * 32);                           \
    float lg0 = s_r + dv.x;                                                   \
    float t0 = fmaxf(lg0, LRELU_ALPHA * lg0);                                 \
    float e0 = ((w0_ >> bp_) & 1u) ? __expf(-t0) : 0.f;                       \
    float lg1 = s_r + dv.y;                                                   \
    float t1 = fmaxf(lg1, LRELU_ALPHA * lg1);                                 \
    float e1 = ((w1_ >> bp_) & 1u) ? __expf(-t1) : 0.f;                       \
    racc += e0 + e1;                                                          \
    u32 pk;                                                                   \
    asm("v_cvt_pk_bf16_f32 %0, %1, %2" : "=v"(pk) : "v"(e0), "v"(e1));        \
    *(u32*)&At[BUF][r * 40 + kp * 2] = pk;                                    \
  }

  __syncthreads();   // Mk visible (full drain once, prologue only)
  EGEN(0, 0)

  // B source: R6-proven 1KB-contiguous wave fragment
  const char* bbase = (const char*)HhTt + (size_t)b * 2097152 + w * 1024 + l * 16;
  int4v Bcur = *(const int4v*)(bbase);

  f32x4 acc[4];
#pragma unroll
  for (int n = 0; n < 4; ++n) acc[n] = (f32x4){0.f, 0.f, 0.f, 0.f};

  for (int st = 0; st < 128; ++st) {
    if (st < 127) EGEN((st + 1) & 3, st + 1)
    const int pst = (st < 127) ? st + 1 : st;
    int4v Bnext = *(const int4v*)(bbase + (size_t)pst * 16384);

    asm volatile("s_waitcnt lgkmcnt(0)" ::: "memory");
    __builtin_amdgcn_s_barrier();
    __builtin_amdgcn_sched_barrier(0);

    const u16* atb = &At[st & 3][0];
    int4v a0 = *(const int4v*)(atb + (0 * 16 + lr) * 40 + lkg * 8);
    int4v a1 = *(const int4v*)(atb + (1 * 16 + lr) * 40 + lkg * 8);
    int4v a2 = *(const int4v*)(atb + (2 * 16 + lr) * 40 + lkg * 8);
    int4v a3 = *(const int4v*)(atb + (3 * 16 + lr) * 40 + lkg * 8);
    bf16x8 bfv = __builtin_bit_cast(bf16x8, Bcur);
    __builtin_amdgcn_s_setprio(1);
    acc[0] = __builtin_amdgcn_mfma_f32_16x16x32_bf16(
        __builtin_bit_cast(bf16x8, a0), bfv, acc[0], 0, 0, 0);
    acc[1] = __builtin_amdgcn_mfma_f32_16x16x32_bf16(
        __builtin_bit_cast(bf16x8, a1), bfv, acc[1], 0, 0, 0);
    acc[2] = __builtin_amdgcn_mfma_f32_16x16x32_bf16(
        __builtin_bit_cast(bf16x8, a2), bfv, acc[2], 0, 0, 0);
    acc[3] = __builtin_amdgcn_mfma_f32_16x16x32_bf16(
        __builtin_bit_cast(bf16x8, a3), bfv, acc[3], 0, 0, 0);
    __builtin_amdgcn_s_setprio(0);
    Bcur = Bnext;
  }
#undef EGEN

  // ---- rowsum: 16 kp-partials per row in one 16-lane group ----
  racc += __shfl_xor(racc, 1);
  racc += __shfl_xor(racc, 2);
  racc += __shfl_xor(racc, 4);
  racc += __shfl_xor(racc, 8);
  if (kp == 0) rs_lds[r] = (racc == 0.f) ? 1.f : racc;
  __syncthreads();

  // ---- epilogue: divide + elu + store (C/D: col=l&15, row=(l>>4)*4+reg) ----
#pragma unroll
  for (int rt = 0; rt < 4; ++rt) {
#pragma unroll
    for (int reg = 0; reg < 4; ++reg) {
      int rloc = rt * 16 + lkg * 4 + reg;
      float rsv = rs_lds[rloc];
      float v = acc[rt][reg] / rsv;
      out[((size_t)(b * 4096 + rowbase + rloc)) * 256 + w * 16 + lr] =
          v > 0.f ? v : (__expf(v) - 1.f);
    }
  }
}

extern "C" void kernel_launch(void* const* d_in, const int* in_sizes, int n_in,
                              void* d_out, int out_size, void* d_ws, size_t ws_size,
                              hipStream_t stream) {
  const float* h = (const float*)d_in[0];
  const int* adj = (const int*)d_in[1];
  const float* W = (const float*)d_in[2];
  const float* a = (const float*)d_in[3];
  float* out = (float*)d_out;

  u16* WbT   = (u16*)d_ws;                                       // 128 KB
  u16* HhTt  = (u16*)((char*)d_ws + 131072);                     // 8 MB
  float* sb  = (float*)((char*)d_ws + 131072 + 8388608);         // 64 KB
  float* db  = sb + 16384;                                       // 64 KB
  u32* maskg = (u32*)((char*)d_ws + 131072 + 8388608 + 131072);  // 8 MB

  hipLaunchKernelGGL(wcast,    dim3(256),  dim3(256),  0, stream, W, WbT);
  hipLaunchKernelGGL(packgemm, dim3(4352), dim3(256),  0, stream,
                     adj, maskg, h, WbT, a, HhTt, sb, db);
  hipLaunchKernelGGL(gat_main, dim3(256),  dim3(1024), 0, stream,
                     maskg, HhTt, sb, db, out);
}